// Round 7
// baseline (315.192 us; speedup 1.0000x reference)
//
#include <hip/hip_runtime.h>
#include <hip/hip_bf16.h>

// SoftSOM: dists = cdist(x, P); W = softmax(-dists/0.4); blended = W @ P
// N=524288 tokens, D=128, M=256 protos. Outputs: blended [N,128] f32, weights [N,256] f32.
//
// Round-7: BARRIER-FREE token-split design.
//  - 128 tok/block, 512 thr (8 waves); wave w owns tokens w*16..w*16+15;
//    lane (c,g) owns token w*16+c end-to-end.
//  - Only sync: one vmcnt(0)+__syncthreads after Plds staging. After that,
//    waves run fully independently (no LDS hazards: Plds/s_psq read-only).
//  - W never touches LDS: softmax result is permuted in-register to MFMA
//    A-fragment order via 64 __shfl + selects (fixed permutation).
//  - Blended uses PT-hi only (single bf16 P): halves blended MFMAs; error
//    budget ~0.025 vs 0.0706 threshold.

#define N_TOK 524288
#define DIM 128
#define M_PROTO 256

typedef __attribute__((ext_vector_type(8))) short bf16x8;
typedef __attribute__((ext_vector_type(4))) float f32x4;

typedef __attribute__((address_space(1))) const unsigned int g_u32;
typedef __attribute__((address_space(3))) unsigned int l_u32;

static __device__ __forceinline__ unsigned short f2bf(float f) {
    unsigned int u = __float_as_uint(f);
    u += 0x7FFFu + ((u >> 16) & 1u);   // round-to-nearest-even
    return (unsigned short)(u >> 16);
}
static __device__ __forceinline__ float bf2f(unsigned short h) {
    return __uint_as_float(((unsigned int)h) << 16);
}
static __device__ __forceinline__ unsigned int pk_bf16(float lo, float hi) {
    unsigned int r;
    asm("v_cvt_pk_bf16_f32 %0, %1, %2" : "=v"(r) : "v"(lo), "v"(hi));
    return r;
}

// ---------------------------------------------------------------------------
// Prep: P -> bf16 fragments.
//  - Cross  A-frag, SINGLE bf16:  PfH[((kt*16+mf)*64+lane)*8+j], linear==LDS.
//  - Blended B-frag, SINGLE bf16: PTfH[((kt2*8+ng)*64+lane)*8+j].
// Also p_sq[256].
// ---------------------------------------------------------------------------
__global__ void __launch_bounds__(128) prep_kernel(
        const float* __restrict__ P,
        unsigned short* __restrict__ PfH,
        unsigned short* __restrict__ PTfH,
        float* __restrict__ psq) {
    int m = blockIdx.x;      // proto 0..255
    int d = threadIdx.x;     // dim   0..127
    float v = P[m * DIM + d];
    unsigned short hi = f2bf(v);

    int ci = (((d >> 5) * 16 + (m >> 4)) * 64 + (((d >> 3) & 3) * 16 + (m & 15))) * 8 + (d & 7);
    PfH[ci] = hi;

    int bi = (((m >> 5) * 8 + (d >> 4)) * 64 + (((m >> 3) & 3) * 16 + (d & 15))) * 8 + (m & 7);
    PTfH[bi] = hi;

    float s = v * v;
    #pragma unroll
    for (int off = 1; off < 64; off <<= 1) s += __shfl_xor(s, off, 64);
    __shared__ float part[2];
    if ((threadIdx.x & 63) == 0) part[threadIdx.x >> 6] = s;
    __syncthreads();
    if (threadIdx.x == 0) psq[m] = part[0] + part[1];
}

// ---------------------------------------------------------------------------
// Main kernel: 128 tokens/block, 512 threads (8 waves, 16 tok/wave).
// LDS: Plds 64 KB + psq 1 KB = 65.5 KB -> 2 blocks/CU. Read-only post-init.
// Flow (per wave, independent after one sync):
//   cross S^T = P @ X^T  (Plds lane-linear b128; X hi/lo in regs)
//   in-register softmax  (lane holds 64 logits of its token; 2 shfl_xor)
//   pack W -> bf16 pairs; in-wave shfl permutation -> A-frags pa[8]
//   weight stores (f32 from pa, 2 adjacent float4/lane/kt)
//   blended = W @ P      (pa x PT-hi from L2; 64 MFMA) + scalar f32 stores
// ---------------------------------------------------------------------------
__global__ void __launch_bounds__(512, 4) softsom_main(
        const float* __restrict__ X,
        const unsigned short* __restrict__ PfH,
        const unsigned short* __restrict__ PTfH,
        const float* __restrict__ psq,
        float* __restrict__ blended, float* __restrict__ weights) {

    __shared__ __align__(16) unsigned short Plds[32768];   // 64 KB, read-only
    __shared__ __align__(16) float s_psq[256];

    const int t = threadIdx.x;
    const int w = t >> 6;          // wave 0..7
    const int l = t & 63;          // lane
    const int c = l & 15;
    const int g = l >> 4;
    const int myrow = w * 16 + c;  // this lane's token row within the tile
    const long base_tok = (long)blockIdx.x * 128;

    // ---- X prefetch (per-lane row, 2 float4 per k-tile) ----
    const float* xrow = X + (base_tok + myrow) * DIM;
    float4 xf[8];
    #pragma unroll
    for (int kt = 0; kt < 4; ++kt) {
        xf[kt * 2]     = *(const float4*)(xrow + kt * 32 + g * 8);
        xf[kt * 2 + 1] = *(const float4*)(xrow + kt * 32 + g * 8 + 4);
    }

    if (t < 256) s_psq[t] = psq[t];

    // ---- Stage PfH (64 KB) -> LDS: 64 chunks of 1 KB, 8 per wave ----
    #pragma unroll
    for (int i = 0; i < 8; ++i) {
        int q = w * 8 + i;
        __builtin_amdgcn_global_load_lds(
            (g_u32*)(PfH + q * 512 + l * 8),
            (l_u32*)(Plds + q * 512),
            16, 0, 0);
    }
    asm volatile("s_waitcnt vmcnt(0)" ::: "memory");
    __syncthreads();   // ONLY barrier: Plds + s_psq ready; LDS read-only after

    // ---- Convert X to bf16 hi/lo, accumulate x_sq ----
    bf16x8 xh[4], xl[4];
    float ps = 0.f;
    #pragma unroll
    for (int kt = 0; kt < 4; ++kt) {
        float xv[8] = {xf[kt*2].x, xf[kt*2].y, xf[kt*2].z, xf[kt*2].w,
                       xf[kt*2+1].x, xf[kt*2+1].y, xf[kt*2+1].z, xf[kt*2+1].w};
        #pragma unroll
        for (int j = 0; j < 8; ++j) {
            ps += xv[j] * xv[j];
            unsigned short h = f2bf(xv[j]);
            xh[kt][j] = (short)h;
            xl[kt][j] = (short)f2bf(xv[j] - bf2f(h));
        }
    }
    ps += __shfl_xor(ps, 16, 64);
    ps += __shfl_xor(ps, 32, 64);
    const float xq = ps;

    // ---- Cross S^T = P @ X^T (A-frags from LDS, lane-linear b128) ----
    f32x4 acc[16];
    #pragma unroll
    for (int m = 0; m < 16; ++m) acc[m] = (f32x4){0.f, 0.f, 0.f, 0.f};

    #pragma unroll
    for (int kt = 0; kt < 4; ++kt) {
        #pragma unroll
        for (int m = 0; m < 16; ++m) {
            bf16x8 ah = *(const bf16x8*)&Plds[((kt * 16 + m) * 64 + l) * 8];
            acc[m] = __builtin_amdgcn_mfma_f32_16x16x32_bf16(ah, xh[kt], acc[m], 0, 0, 0);
            acc[m] = __builtin_amdgcn_mfma_f32_16x16x32_bf16(ah, xl[kt], acc[m], 0, 0, 0);
        }
    }

    // ---- Softmax over protos (exp2 domain) ----
    // lane (c,g) holds logits of token myrow: protos m*16 + g*4 + r
    const float K2 = 3.6067376022224085f;  // (1/0.4) * log2(e)
    float mx = -3.4e38f;
    #pragma unroll
    for (int m = 0; m < 16; ++m) {
        f32x4 pq = *(const f32x4*)&s_psq[m * 16 + g * 4];
        #pragma unroll
        for (int r = 0; r < 4; ++r) {
            float s2 = fmaxf(xq + pq[r] - 2.f * acc[m][r], 0.f);
            float lg = -sqrtf(s2) * K2;
            acc[m][r] = lg;
            mx = fmaxf(mx, lg);
        }
    }
    mx = fmaxf(mx, __shfl_xor(mx, 16, 64));
    mx = fmaxf(mx, __shfl_xor(mx, 32, 64));
    float sum = 0.f;
    #pragma unroll
    for (int m = 0; m < 16; ++m) {
        #pragma unroll
        for (int r = 0; r < 4; ++r) {
            float p = exp2f(acc[m][r] - mx);
            acc[m][r] = p;
            sum += p;
        }
    }
    sum += __shfl_xor(sum, 16, 64);
    sum += __shfl_xor(sum, 32, 64);
    const float inv = 1.0f / sum;

    // ---- Pack W (x inv) to bf16 pairs: u0[m]={w0,w1}, u1[m]={w2,w3} ----
    int u0[16], u1[16];
    #pragma unroll
    for (int m = 0; m < 16; ++m) {
        u0[m] = (int)pk_bf16(acc[m][0] * inv, acc[m][1] * inv);
        u1[m] = (int)pk_bf16(acc[m][2] * inv, acc[m][3] * inv);
    }

    // ---- In-wave permutation -> A-frags pa[kt] = W[c][kt*32 + 8g + 0..7] ----
    // word q of pa[kt] = u_{q&1}[2kt + (g>>1)] from lane c + 32*(g&1) + 16*(q>>1)
    const int sel  = g >> 1;
    const int srcA = c + 32 * (g & 1);
    const int srcB = srcA + 16;
    bf16x8 pa[8];
    #pragma unroll
    for (int kt = 0; kt < 8; ++kt) {
        int a0 = __shfl(u0[2 * kt],     srcA, 64);
        int a1 = __shfl(u1[2 * kt],     srcA, 64);
        int b0 = __shfl(u0[2 * kt + 1], srcA, 64);
        int b1 = __shfl(u1[2 * kt + 1], srcA, 64);
        int c0 = __shfl(u0[2 * kt],     srcB, 64);
        int c1 = __shfl(u1[2 * kt],     srcB, 64);
        int d0 = __shfl(u0[2 * kt + 1], srcB, 64);
        int d1 = __shfl(u1[2 * kt + 1], srcB, 64);
        int4 tmp;
        tmp.x = sel ? b0 : a0;
        tmp.y = sel ? b1 : a1;
        tmp.z = sel ? d0 : c0;
        tmp.w = sel ? d1 : c1;
        pa[kt] = *(bf16x8*)&tmp;
    }

    // ---- Weight stores: f32 from pa (lane covers 32B-contiguous protos) ----
    {
        float* wout = weights + (base_tok + myrow) * M_PROTO + g * 8;
        #pragma unroll
        for (int kt = 0; kt < 8; ++kt) {
            float4 o0 = {bf2f((unsigned short)pa[kt][0]), bf2f((unsigned short)pa[kt][1]),
                         bf2f((unsigned short)pa[kt][2]), bf2f((unsigned short)pa[kt][3])};
            float4 o1 = {bf2f((unsigned short)pa[kt][4]), bf2f((unsigned short)pa[kt][5]),
                         bf2f((unsigned short)pa[kt][6]), bf2f((unsigned short)pa[kt][7])};
            *(float4*)&wout[kt * 32]     = o0;
            *(float4*)&wout[kt * 32 + 4] = o1;
        }
    }

    // ---- Blended = W @ P (token-split: wave's 16 tokens x all 128 cols) ----
    // B-frags from L2-resident PT-hi (identical addresses across waves).
    f32x4 acc2[8];
    #pragma unroll
    for (int ng = 0; ng < 8; ++ng) acc2[ng] = (f32x4){0.f, 0.f, 0.f, 0.f};

    const bf16x8* pth = (const bf16x8*)PTfH;
    #pragma unroll
    for (int kt = 0; kt < 8; ++kt) {
        #pragma unroll
        for (int ng = 0; ng < 8; ++ng) {
            bf16x8 bh = pth[(kt * 8 + ng) * 64 + l];
            acc2[ng] = __builtin_amdgcn_mfma_f32_16x16x32_bf16(pa[kt], bh, acc2[ng], 0, 0, 0);
        }
    }

    // D-layout: lane (c,g) reg r holds blended[token w*16 + g*4 + r][ng*16 + c]
    {
        float* bout = blended + (base_tok + w * 16) * DIM;
        #pragma unroll
        for (int ng = 0; ng < 8; ++ng)
            #pragma unroll
            for (int r = 0; r < 4; ++r)
                bout[(g * 4 + r) * DIM + ng * 16 + c] = acc2[ng][r];
    }
}

extern "C" void kernel_launch(void* const* d_in, const int* in_sizes, int n_in,
                              void* d_out, int out_size, void* d_ws, size_t ws_size,
                              hipStream_t stream) {
    const float* x = (const float*)d_in[0];
    const float* protos = (const float*)d_in[1];

    float* out = (float*)d_out;
    float* blended = out;                               // [N,128]
    float* weights = out + (size_t)N_TOK * DIM;         // [N,256]

    unsigned short* PfH  = (unsigned short*)d_ws;       // 32768 elems each
    unsigned short* PTfH = PfH  + 32768;
    float*          psq  = (float*)(PTfH + 32768);      // 256 f32

    prep_kernel<<<M_PROTO, DIM, 0, stream>>>(protos, PfH, PTfH, psq);
    softsom_main<<<N_TOK / 128, 512, 0, stream>>>(x, PfH, PTfH, psq,
                                                  blended, weights);
}

// Round 8
// 239.429 us; speedup vs baseline: 1.3164x; 1.3164x over previous
//
#include <hip/hip_runtime.h>
#include <hip/hip_bf16.h>

// SoftSOM: dists = cdist(x, P); W = softmax(-dists/0.4); blended = W @ P
// N=524288 tokens, D=128, M=256 protos. Outputs: blended [N,128] f32, weights [N,256] f32.
//
// Round-8 = Round-4 skeleton (best measured: 277 us) with arithmetic halved:
//  - cross: P-hi x X-hi only (1 MFMA/frag, 512/block)     [was 2/frag]
//  - blended: PT-hi only     (1 MFMA/frag, 512/block)     [was 2/frag]
//  - blended B-frag loads issued before weight readback (latency hidden)
// Sync structure, LDS layout, store paths identical to round 4.

#define N_TOK 524288
#define DIM 128
#define M_PROTO 256

typedef __attribute__((ext_vector_type(8))) short bf16x8;
typedef __attribute__((ext_vector_type(4))) float f32x4;
typedef __attribute__((ext_vector_type(4))) unsigned short us4;

typedef __attribute__((address_space(1))) const unsigned int g_u32;
typedef __attribute__((address_space(3))) unsigned int l_u32;

static __device__ __forceinline__ unsigned short f2bf(float f) {
    unsigned int u = __float_as_uint(f);
    u += 0x7FFFu + ((u >> 16) & 1u);   // round-to-nearest-even
    return (unsigned short)(u >> 16);
}
static __device__ __forceinline__ float bf2f(unsigned short h) {
    return __uint_as_float(((unsigned int)h) << 16);
}

// ---------------------------------------------------------------------------
// Prep: P -> bf16 fragments.
//  - Cross  A-frag:  PfH[((kt*16+mf)*64+lane)*8+j], linear == LDS image.
//  - Blended B-frag: PTfH[((kt2*8+ng)*64+lane)*8+j].
// Also p_sq[256].
// ---------------------------------------------------------------------------
__global__ void __launch_bounds__(128) prep_kernel(
        const float* __restrict__ P,
        unsigned short* __restrict__ PfH,
        unsigned short* __restrict__ PTfH,
        float* __restrict__ psq) {
    int m = blockIdx.x;      // proto 0..255
    int d = threadIdx.x;     // dim   0..127
    float v = P[m * DIM + d];
    unsigned short hi = f2bf(v);

    int ci = (((d >> 5) * 16 + (m >> 4)) * 64 + (((d >> 3) & 3) * 16 + (m & 15))) * 8 + (d & 7);
    PfH[ci] = hi;

    int bi = (((m >> 5) * 8 + (d >> 4)) * 64 + (((m >> 3) & 3) * 16 + (d & 15))) * 8 + (m & 7);
    PTfH[bi] = hi;

    float s = v * v;
    #pragma unroll
    for (int off = 1; off < 64; off <<= 1) s += __shfl_xor(s, off, 64);
    __shared__ float part[2];
    if ((threadIdx.x & 63) == 0) part[threadIdx.x >> 6] = s;
    __syncthreads();
    if (threadIdx.x == 0) psq[m] = part[0] + part[1];
}

// ---------------------------------------------------------------------------
// Main kernel: 128 tokens/block, 512 threads (8 waves, 16 tok/wave).
// LDS: smem 64 KB (Plds cross-P frags, ALIASED with Wl[128][264] after
//      barrier) + psq 1 KB -> ~66 KB -> 2 blocks/CU, VGPR capped 128.
// Flow: [X prefetch + stage Plds] vmcnt(0)+syncthreads
//       cross S^T = P @ X^T   (Plds lane-linear b128; X single-bf16 regs)
//       softmax in-register   (exp2 domain; 2 shfl_xor)
//       syncthreads           (all Plds reads done before Wl overwrite)
//       Wl writes (bf16)
//       syncthreads
//       blended B-frag loads -> weight readback (coalesced 1KB-row f32
//       stores) -> blended = W @ P (single MFMA/frag) -> f32 stores
// ---------------------------------------------------------------------------
__global__ void __launch_bounds__(512, 4) softsom_main(
        const float* __restrict__ X,
        const unsigned short* __restrict__ PfH,
        const unsigned short* __restrict__ PTfH,
        const float* __restrict__ psq,
        float* __restrict__ blended, float* __restrict__ weights) {

    __shared__ __align__(16) unsigned short smem[33792];   // 66 KB: Plds | Wl
    __shared__ float s_psq[256];
    unsigned short* Plds = smem;
    unsigned short (*Wl)[264] = (unsigned short (*)[264])smem;

    const int t = threadIdx.x;
    const int w = t >> 6;          // wave 0..7
    const int l = t & 63;          // lane
    const int c = l & 15;
    const int g = l >> 4;
    const int myrow = w * 16 + c;  // this lane's token row within the tile
    const long base_tok = (long)blockIdx.x * 128;

    // ---- X prefetch (per-lane row, 2 float4 per k-tile) ----
    const float* xrow = X + (base_tok + myrow) * DIM;
    float4 xf[8];
    #pragma unroll
    for (int kt = 0; kt < 4; ++kt) {
        xf[kt * 2]     = *(const float4*)(xrow + kt * 32 + g * 8);
        xf[kt * 2 + 1] = *(const float4*)(xrow + kt * 32 + g * 8 + 4);
    }

    if (t < 256) s_psq[t] = psq[t];

    // ---- Stage PfH (64 KB) -> LDS: 64 chunks of 1 KB, 8 per wave ----
    #pragma unroll
    for (int i = 0; i < 8; ++i) {
        int q = w * 8 + i;
        __builtin_amdgcn_global_load_lds(
            (g_u32*)(PfH + q * 512 + l * 8),
            (l_u32*)(Plds + q * 512),
            16, 0, 0);
    }
    asm volatile("s_waitcnt vmcnt(0)" ::: "memory");
    __syncthreads();

    // ---- Convert X to single bf16, accumulate exact f32 x_sq ----
    bf16x8 xh[4];
    float ps = 0.f;
    #pragma unroll
    for (int kt = 0; kt < 4; ++kt) {
        float xv[8] = {xf[kt*2].x, xf[kt*2].y, xf[kt*2].z, xf[kt*2].w,
                       xf[kt*2+1].x, xf[kt*2+1].y, xf[kt*2+1].z, xf[kt*2+1].w};
        #pragma unroll
        for (int j = 0; j < 8; ++j) {
            ps += xv[j] * xv[j];
            xh[kt][j] = (short)f2bf(xv[j]);
        }
    }
    ps += __shfl_xor(ps, 16, 64);
    ps += __shfl_xor(ps, 32, 64);
    const float xq = ps;

    // ---- Cross S^T = P @ X^T (A-frags from LDS, lane-linear b128) ----
    f32x4 acc[16];
    #pragma unroll
    for (int m = 0; m < 16; ++m) acc[m] = (f32x4){0.f, 0.f, 0.f, 0.f};

    #pragma unroll
    for (int kt = 0; kt < 4; ++kt) {
        #pragma unroll
        for (int m = 0; m < 16; ++m) {
            bf16x8 ah = *(const bf16x8*)&Plds[((kt * 16 + m) * 64 + l) * 8];
            acc[m] = __builtin_amdgcn_mfma_f32_16x16x32_bf16(ah, xh[kt], acc[m], 0, 0, 0);
        }
    }

    // ---- Softmax over protos (exp2 domain) ----
    const float K2 = 3.6067376022224085f;  // (1/0.4) * log2(e)
    float mx = -3.4e38f;
    #pragma unroll
    for (int m = 0; m < 16; ++m) {
        f32x4 pq = *(const f32x4*)&s_psq[m * 16 + g * 4];
        #pragma unroll
        for (int r = 0; r < 4; ++r) {
            float s2 = fmaxf(xq + pq[r] - 2.f * acc[m][r], 0.f);
            float lg = -sqrtf(s2) * K2;
            acc[m][r] = lg;
            mx = fmaxf(mx, lg);
        }
    }
    mx = fmaxf(mx, __shfl_xor(mx, 16, 64));
    mx = fmaxf(mx, __shfl_xor(mx, 32, 64));
    float sum = 0.f;
    #pragma unroll
    for (int m = 0; m < 16; ++m) {
        #pragma unroll
        for (int r = 0; r < 4; ++r) {
            float p = exp2f(acc[m][r] - mx);
            acc[m][r] = p;
            sum += p;
        }
    }
    sum += __shfl_xor(sum, 16, 64);
    sum += __shfl_xor(sum, 32, 64);
    const float inv = 1.0f / sum;

    // ---- Barrier: all Plds reads done before Wl (alias) is written ----
    __syncthreads();

    // ---- W -> LDS (bf16) ----
    #pragma unroll
    for (int m = 0; m < 16; ++m) {
        us4 wv = {f2bf(acc[m][0] * inv), f2bf(acc[m][1] * inv),
                  f2bf(acc[m][2] * inv), f2bf(acc[m][3] * inv)};
        *(us4*)&Wl[myrow][m * 16 + g * 4] = wv;
    }
    __syncthreads();

    // ---- Blended B-frags first (L2; latency hides under readback) ----
    const bf16x8* pth = (const bf16x8*)PTfH;
    bf16x8 bh[8];
    #pragma unroll
    for (int kt = 0; kt < 8; ++kt)
        bh[kt] = pth[(kt * 8 + w) * 64 + l];

    // ---- Weight stores: coalesced 1KB-row f32 from Wl readback ----
    {
        float* wout = weights + base_tok * M_PROTO;
        #pragma unroll
        for (int i = 0; i < 16; ++i) {
            int idx = i * 512 + t;
            int row = idx >> 6;
            int c4  = (idx & 63) * 4;
            us4 wv = *(const us4*)&Wl[row][c4];
            float4 o = {bf2f(wv[0]), bf2f(wv[1]), bf2f(wv[2]), bf2f(wv[3])};
            *(float4*)&wout[row * M_PROTO + c4] = o;
        }
    }

    // ---- Blended = W @ P (K=256; wave w owns cols w*16..w*16+15) ----
    f32x4 acc2[8];
    #pragma unroll
    for (int m = 0; m < 8; ++m) acc2[m] = (f32x4){0.f, 0.f, 0.f, 0.f};

    #pragma unroll
    for (int kt = 0; kt < 8; ++kt) {
        #pragma unroll
        for (int m = 0; m < 8; ++m) {
            bf16x8 aw = *(const bf16x8*)&Wl[m * 16 + c][kt * 32 + g * 8];
            acc2[m] = __builtin_amdgcn_mfma_f32_16x16x32_bf16(aw, bh[kt], acc2[m], 0, 0, 0);
        }
    }

    {
        float* bout = blended + base_tok * DIM + w * 16 + c;
        #pragma unroll
        for (int m = 0; m < 8; ++m)
            #pragma unroll
            for (int r = 0; r < 4; ++r) {
                int row = m * 16 + g * 4 + r;
                bout[row * DIM] = acc2[m][r];
            }
    }
}

extern "C" void kernel_launch(void* const* d_in, const int* in_sizes, int n_in,
                              void* d_out, int out_size, void* d_ws, size_t ws_size,
                              hipStream_t stream) {
    const float* x = (const float*)d_in[0];
    const float* protos = (const float*)d_in[1];

    float* out = (float*)d_out;
    float* blended = out;                               // [N,128]
    float* weights = out + (size_t)N_TOK * DIM;         // [N,256]

    unsigned short* PfH  = (unsigned short*)d_ws;       // 32768 elems each
    unsigned short* PTfH = PfH  + 32768;
    float*          psq  = (float*)(PTfH + 32768);      // 256 f32

    prep_kernel<<<M_PROTO, DIM, 0, stream>>>(protos, PfH, PTfH, psq);
    softsom_main<<<N_TOK / 128, 512, 0, stream>>>(x, PfH, PTfH, psq,
                                                  blended, weights);
}